// Round 2
// baseline (313.910 us; speedup 1.0000x reference)
//
#include <hip/hip_runtime.h>

typedef unsigned short u16;
typedef __attribute__((ext_vector_type(8))) short bf16x8;
typedef __attribute__((ext_vector_type(4))) float f32x4;
typedef __attribute__((ext_vector_type(4))) unsigned short u16x4;

#define B_  2
#define S_  2048
#define H_  1024
#define NH_ 16
#define HD_ 64
#define MR_ (B_*S_)   /* 4096 rows */
#define K_  H_

__device__ __forceinline__ u16 f2bf(float f) {
  union { float f; unsigned u; } x; x.f = f;
  unsigned r = x.u + 0x7fffu + ((x.u >> 16) & 1u);
  return (u16)(r >> 16);
}

__device__ __forceinline__ void gload16(const u16* g, u16* l) {
  __builtin_amdgcn_global_load_lds((const __attribute__((address_space(1))) void*)g,
                                   (__attribute__((address_space(3))) void*)l, 16, 0, 0);
}

// ---------------- convert q,k,v f32 -> bf16 ----------------
__global__ __launch_bounds__(256) void cvt3(const float* __restrict__ q, const float* __restrict__ k,
                                            const float* __restrict__ v, u16* __restrict__ dst) {
  const float* src = blockIdx.z == 0 ? q : blockIdx.z == 1 ? k : v;
  u16* d = dst + (size_t)blockIdx.z * MR_ * H_;
  size_t i = ((size_t)blockIdx.x * 256 + threadIdx.x) * 4;
  float4 f = *(const float4*)(src + i);
  u16x4 o = { f2bf(f.x), f2bf(f.y), f2bf(f.z), f2bf(f.w) };
  *(u16x4*)(d + i) = o;
}

// ---------------- transpose + convert weights: Wt[n][k] = bf16(W[k][n]) ----------------
__global__ __launch_bounds__(256) void wtrans(const float* __restrict__ Wq, const float* __restrict__ Wk,
                                              const float* __restrict__ Wv, const float* __restrict__ Wo,
                                              u16* __restrict__ wt) {
  const int z = blockIdx.z;
  const float* W = z == 0 ? Wq : z == 1 ? Wk : z == 2 ? Wv : Wo;
  u16* Wt = wt + (size_t)z * H_ * K_;
  __shared__ float t[32][33];
  const int n0 = blockIdx.x * 32, k0 = blockIdx.y * 32;
  const int tx = threadIdx.x & 31, ty = threadIdx.x >> 5;  // ty 0..7
  #pragma unroll
  for (int i = 0; i < 4; i++) t[ty + 8*i][tx] = W[(size_t)(k0 + ty + 8*i) * H_ + n0 + tx];
  __syncthreads();
  #pragma unroll
  for (int i = 0; i < 4; i++) Wt[(size_t)(n0 + ty + 8*i) * K_ + k0 + tx] = f2bf(t[tx][ty + 8*i]);
}

// ---------------- GEMM body: A[M,K] bf16 row-major, Bt[N,K] bf16 row-major ----------------
// 128x128 tile, BK=64, 256 threads (4 waves, 2x2), mfma_f32_16x16x32_bf16.
// MODE 0: bf16 out row-major (scaled); MODE 1: f32 out; MODE 2: bf16 V^T out [bh][d][s].
template <int MODE>
__device__ __forceinline__ void gemm_body(const u16* __restrict__ A, const u16* __restrict__ Bt,
                                          const float* __restrict__ bias, float scale,
                                          u16* __restrict__ Obf, float* __restrict__ Of,
                                          int m_tile, int n_tile) {
  __shared__ u16 ldsA[128 * 64];
  __shared__ u16 ldsB[128 * 64];
  const int tid = threadIdx.x;
  const int lane = tid & 63, wave = tid >> 6;
  const int wm = wave >> 1, wn = wave & 1;
  const int m0 = m_tile * 128, n0 = n_tile * 128;

  f32x4 acc[4][4] = {};

  const int srow = tid >> 3;                     // 0..31
  const int sslot = (tid & 7) ^ (srow & 7);      // logical k-slot to fetch (pre-swizzled source)
  const u16* ga = A + (size_t)(m0 + srow) * K_ + sslot * 8;
  const u16* gb = Bt + (size_t)(n0 + srow) * K_ + sslot * 8;
  u16* la = ldsA + tid * 8;
  u16* lb = ldsB + tid * 8;

  const int fr = lane & 15;   // fragment row (A: m, B: n)
  const int kg = lane >> 4;   // k-group 0..3

  for (int k0 = 0; k0 < K_; k0 += 64) {
    #pragma unroll
    for (int j = 0; j < 4; j++) gload16(ga + (size_t)(j * 32) * K_ + k0, la + j * 2048);
    #pragma unroll
    for (int j = 0; j < 4; j++) gload16(gb + (size_t)(j * 32) * K_ + k0, lb + j * 2048);
    __syncthreads();

    #pragma unroll
    for (int kk = 0; kk < 2; kk++) {
      const int ps = (((kk << 2) | kg) ^ (fr & 7)) * 8;   // swizzled read
      bf16x8 a[4], b[4];
      #pragma unroll
      for (int mf = 0; mf < 4; mf++)
        a[mf] = *(const bf16x8*)&ldsA[(wm * 64 + mf * 16 + fr) * 64 + ps];
      #pragma unroll
      for (int nf = 0; nf < 4; nf++)
        b[nf] = *(const bf16x8*)&ldsB[(wn * 64 + nf * 16 + fr) * 64 + ps];
      #pragma unroll
      for (int mf = 0; mf < 4; mf++)
        #pragma unroll
        for (int nf = 0; nf < 4; nf++)
          acc[mf][nf] = __builtin_amdgcn_mfma_f32_16x16x32_bf16(a[mf], b[nf], acc[mf][nf], 0, 0, 0);
    }
    __syncthreads();
  }

  float bcol[4];
  #pragma unroll
  for (int nf = 0; nf < 4; nf++) bcol[nf] = bias[n0 + wn * 64 + nf * 16 + fr];

  if (MODE == 2) {
    // V^T store: out[((b*16+h)*64+d)*2048 + s], col=h*64+d, row=b*2048+s.
    // acc rows r=0..3 are s-consecutive -> 8B packed stores.
    #pragma unroll
    for (int mf = 0; mf < 4; mf++) {
      const int row0 = m0 + wm * 64 + mf * 16 + kg * 4;
      #pragma unroll
      for (int nf = 0; nf < 4; nf++) {
        const int col = n0 + wn * 64 + nf * 16 + fr;
        u16x4 o;
        #pragma unroll
        for (int r = 0; r < 4; r++) o[r] = f2bf(acc[mf][nf][r] + bcol[nf]);
        size_t idx = (((size_t)(col + ((row0 >> 11) << 10))) << 11) + (row0 & 2047);
        *(u16x4*)(Obf + idx) = o;
      }
    }
  } else {
    #pragma unroll
    for (int mf = 0; mf < 4; mf++)
      #pragma unroll
      for (int r = 0; r < 4; r++) {
        const int row = m0 + wm * 64 + mf * 16 + kg * 4 + r;
        #pragma unroll
        for (int nf = 0; nf < 4; nf++) {
          const int col = n0 + wn * 64 + nf * 16 + fr;
          float val = (acc[mf][nf][r] + bcol[nf]) * scale;
          if (MODE == 0) Obf[(size_t)row * H_ + col] = f2bf(val);
          else           Of [(size_t)row * H_ + col] = val;
        }
      }
  }
}

__global__ __launch_bounds__(256) void gemm_qkv(const u16* __restrict__ xb, const u16* __restrict__ wt,
                                                const float* __restrict__ b0, const float* __restrict__ b1,
                                                const float* __restrict__ b2,
                                                u16* __restrict__ QKo, u16* __restrict__ VTo) {
  const int z = blockIdx.z;
  const u16* A = xb + (size_t)z * MR_ * K_;
  const u16* Bt = wt + (size_t)z * H_ * K_;
  if (z == 2) {
    gemm_body<2>(A, Bt, b2, 1.0f, VTo, nullptr, blockIdx.y, blockIdx.x);
  } else {
    const float* bias = z == 0 ? b0 : b1;
    const float scale = z == 0 ? 0.125f : 1.0f;   // fold 1/sqrt(HD) into Q (exponent-exact)
    gemm_body<0>(A, Bt, bias, scale, QKo + (size_t)z * MR_ * H_, nullptr, blockIdx.y, blockIdx.x);
  }
}

__global__ __launch_bounds__(256) void gemm_out(const u16* __restrict__ ctx, const u16* __restrict__ wot,
                                                const float* __restrict__ bo, float* __restrict__ out) {
  gemm_body<1>(ctx, wot, bo, 1.0f, nullptr, out, blockIdx.y, blockIdx.x);
}

// ---------------- flash attention: 4 waves x 16 q-rows, KVBLK=64, no barriers ----------------
// K fragments direct from global (d-contiguous); V^T fragments direct from global (s-contiguous);
// P staged through per-wave swizzled LDS (wave-synchronous, in-order DS pipe, no __syncthreads).
__global__ __launch_bounds__(256) void attn(const u16* __restrict__ qp, const u16* __restrict__ kp,
                                            const u16* __restrict__ vt, u16* __restrict__ ctx) {
  __shared__ u16 Plds[4][16 * 64];   // per-wave P tile, swizzled (slot ^= row&7)
  const int bh = blockIdx.y;
  const int b = bh >> 4, h = bh & 15;
  const int q0 = blockIdx.x * 64;
  const int tid = threadIdx.x;
  const int wave = tid >> 6, lane = tid & 63;
  const int fr = lane & 15, kg = lane >> 4;

  const u16* Q  = qp + (size_t)b * S_ * H_ + h * HD_;
  const u16* Kb = kp + (size_t)b * S_ * H_ + h * HD_;
  const u16* Vt = vt + (size_t)bh * HD_ * S_;
  u16* O = ctx + (size_t)b * S_ * H_ + h * HD_;
  u16* Pw = Plds[wave];

  const int qrow = q0 + wave * 16 + fr;
  bf16x8 qf[2];
  qf[0] = *(const bf16x8*)&Q[(size_t)qrow * H_ + kg * 8];
  qf[1] = *(const bf16x8*)&Q[(size_t)qrow * H_ + 32 + kg * 8];

  f32x4 oacc[4] = {};
  float mrow[4], lrow[4];
  #pragma unroll
  for (int r = 0; r < 4; r++) { mrow[r] = -1e30f; lrow[r] = 0.f; }

  for (int s0 = 0; s0 < S_; s0 += 64) {
    // QK^T: A=Q (16 q rows), B=K^T (s-cols, d-contiguous from global). sc[cf]: D[q][s=cf*16+fr]
    f32x4 sc[4] = {};
    #pragma unroll
    for (int cf = 0; cf < 4; cf++)
      #pragma unroll
      for (int kk = 0; kk < 2; kk++) {
        bf16x8 kf = *(const bf16x8*)&Kb[(size_t)(s0 + cf * 16 + fr) * H_ + kk * 32 + kg * 8];
        sc[cf] = __builtin_amdgcn_mfma_f32_16x16x32_bf16(qf[kk], kf, sc[cf], 0, 0, 0);
      }
    // online softmax over s (16-lane fr-group reductions); rows q = kg*4+r
    float tmax[4], psum[4], sf[4], p[4][4];
    #pragma unroll
    for (int r = 0; r < 4; r++)
      tmax[r] = fmaxf(fmaxf(sc[0][r], sc[1][r]), fmaxf(sc[2][r], sc[3][r]));
    #pragma unroll
    for (int off = 1; off < 16; off <<= 1)
      #pragma unroll
      for (int r = 0; r < 4; r++) tmax[r] = fmaxf(tmax[r], __shfl_xor(tmax[r], off, 64));
    #pragma unroll
    for (int r = 0; r < 4; r++) {
      float mn = fmaxf(mrow[r], tmax[r]);
      sf[r] = __expf(mrow[r] - mn);
      mrow[r] = mn;
      float s = 0.f;
      #pragma unroll
      for (int cf = 0; cf < 4; cf++) { p[cf][r] = __expf(sc[cf][r] - mn); s += p[cf][r]; }
      psum[r] = s;
    }
    #pragma unroll
    for (int off = 1; off < 16; off <<= 1)
      #pragma unroll
      for (int r = 0; r < 4; r++) psum[r] += __shfl_xor(psum[r], off, 64);
    #pragma unroll
    for (int r = 0; r < 4; r++) {
      lrow[r] = lrow[r] * sf[r] + psum[r];
      #pragma unroll
      for (int nf = 0; nf < 4; nf++) oacc[nf][r] *= sf[r];
    }
    // write P tile (bf16, swizzled): row q=kg*4+r, col s=cf*16+fr
    #pragma unroll
    for (int r = 0; r < 4; r++) {
      const int prow = kg * 4 + r, sw = prow & 7;
      #pragma unroll
      for (int cf = 0; cf < 4; cf++) {
        const int c = cf * 16 + fr;
        Pw[prow * 64 + (((c >> 3) ^ sw) << 3) + (c & 7)] = f2bf(p[cf][r]);
      }
    }
    // PV: A=P[q][s] from own-wave LDS, B=V^T[d][s] from global
    #pragma unroll
    for (int kk = 0; kk < 2; kk++) {
      bf16x8 pf = *(const bf16x8*)&Pw[fr * 64 + ((((kk << 2) | kg) ^ (fr & 7)) << 3)];
      #pragma unroll
      for (int nf = 0; nf < 4; nf++) {
        bf16x8 vf = *(const bf16x8*)&Vt[(size_t)(nf * 16 + fr) * S_ + s0 + kk * 32 + kg * 8];
        oacc[nf] = __builtin_amdgcn_mfma_f32_16x16x32_bf16(pf, vf, oacc[nf], 0, 0, 0);
      }
    }
  }
  // epilogue: O / l -> ctx (bf16)
  float rinv[4];
  #pragma unroll
  for (int r = 0; r < 4; r++) rinv[r] = 1.0f / lrow[r];
  #pragma unroll
  for (int nf = 0; nf < 4; nf++)
    #pragma unroll
    for (int r = 0; r < 4; r++) {
      int row = q0 + wave * 16 + kg * 4 + r;
      O[(size_t)row * H_ + nf * 16 + fr] = f2bf(oacc[nf][r] * rinv[r]);
    }
}

extern "C" void kernel_launch(void* const* d_in, const int* in_sizes, int n_in,
                              void* d_out, int out_size, void* d_ws, size_t ws_size,
                              hipStream_t stream) {
  const float* q  = (const float*)d_in[0];
  const float* k  = (const float*)d_in[1];
  const float* v  = (const float*)d_in[2];
  const float* Wq = (const float*)d_in[3];
  const float* bq = (const float*)d_in[4];
  const float* Wk = (const float*)d_in[5];
  const float* bk = (const float*)d_in[6];
  const float* Wv = (const float*)d_in[7];
  const float* bv = (const float*)d_in[8];
  const float* Wo = (const float*)d_in[9];
  const float* bo = (const float*)d_in[10];
  float* out = (float*)d_out;

  char* ws = (char*)d_ws;
  const size_t MB = 1024 * 1024;
  u16* xb   = (u16*)(ws);             // q,k,v bf16: 3 x 8MB      [0,24)
  u16* wt   = (u16*)(ws + 24 * MB);   // 4 x 2MB transposed W     [24,32)
  u16* qkp  = (u16*)(ws + 32 * MB);   // qp,kp: 2 x 8MB           [32,48)
  u16* vtp  = (u16*)(ws + 48 * MB);   // V^T [bh][d][s]: 8MB      [48,56)
  u16* ctx  = (u16*)(ws);             // reuse xb region after gemm_qkv

  cvt3  <<<dim3(4096, 1, 3), 256, 0, stream>>>(q, k, v, xb);
  wtrans<<<dim3(32, 32, 4),  256, 0, stream>>>(Wq, Wk, Wv, Wo, wt);
  gemm_qkv<<<dim3(8, 32, 3), 256, 0, stream>>>(xb, wt, bq, bk, bv, qkp, vtp);
  attn  <<<dim3(32, 32),     256, 0, stream>>>(qkp, qkp + (size_t)MR_ * H_, vtp, ctx);
  gemm_out<<<dim3(8, 32, 1), 256, 0, stream>>>(ctx, wt + (size_t)3 * H_ * K_, bo, out);
}

// Round 3
// 201.126 us; speedup vs baseline: 1.5608x; 1.5608x over previous
//
#include <hip/hip_runtime.h>

typedef unsigned short u16;
typedef __attribute__((ext_vector_type(8))) short bf16x8;
typedef __attribute__((ext_vector_type(4))) float f32x4;
typedef __attribute__((ext_vector_type(4))) unsigned short u16x4;

#define B_  2
#define S_  2048
#define H_  1024
#define NH_ 16
#define HD_ 64
#define MR_ (B_*S_)   /* 4096 rows */
#define K_  H_

__device__ __forceinline__ u16 f2bf(float f) {
  union { float f; unsigned u; } x; x.f = f;
  unsigned r = x.u + 0x7fffu + ((x.u >> 16) & 1u);
  return (u16)(r >> 16);
}

__device__ __forceinline__ void gload16(const u16* g, u16* l) {
  __builtin_amdgcn_global_load_lds((const __attribute__((address_space(1))) void*)g,
                                   (__attribute__((address_space(3))) void*)l, 16, 0, 0);
}

// ---------------- convert q,k,v f32 -> bf16 ----------------
__global__ __launch_bounds__(256) void cvt3(const float* __restrict__ q, const float* __restrict__ k,
                                            const float* __restrict__ v, u16* __restrict__ dst) {
  const float* src = blockIdx.z == 0 ? q : blockIdx.z == 1 ? k : v;
  u16* d = dst + (size_t)blockIdx.z * MR_ * H_;
  size_t i = ((size_t)blockIdx.x * 256 + threadIdx.x) * 4;
  float4 f = *(const float4*)(src + i);
  u16x4 o = { f2bf(f.x), f2bf(f.y), f2bf(f.z), f2bf(f.w) };
  *(u16x4*)(d + i) = o;
}

// ---------------- transpose + convert weights: Wt[n][k] = bf16(W[k][n]) ----------------
__global__ __launch_bounds__(256) void wtrans(const float* __restrict__ Wq, const float* __restrict__ Wk,
                                              const float* __restrict__ Wv, const float* __restrict__ Wo,
                                              u16* __restrict__ wt) {
  const int z = blockIdx.z;
  const float* W = z == 0 ? Wq : z == 1 ? Wk : z == 2 ? Wv : Wo;
  u16* Wt = wt + (size_t)z * H_ * K_;
  __shared__ float t[32][33];
  const int n0 = blockIdx.x * 32, k0 = blockIdx.y * 32;
  const int tx = threadIdx.x & 31, ty = threadIdx.x >> 5;  // ty 0..7
  #pragma unroll
  for (int i = 0; i < 4; i++) t[ty + 8*i][tx] = W[(size_t)(k0 + ty + 8*i) * H_ + n0 + tx];
  __syncthreads();
  #pragma unroll
  for (int i = 0; i < 4; i++) Wt[(size_t)(n0 + ty + 8*i) * K_ + k0 + tx] = f2bf(t[tx][ty + 8*i]);
}

// ---------------- GEMM body: A[M,K] bf16 row-major, Bt[N,K] bf16 row-major ----------------
// 128x128 tile, BK=64, 256 threads (4 waves, 2x2), mfma_f32_16x16x32_bf16.
// MODE 0: bf16 out row-major (scaled); MODE 1: f32 out; MODE 2: bf16 V^T out [bh][d][s].
template <int MODE>
__device__ __forceinline__ void gemm_body(const u16* __restrict__ A, const u16* __restrict__ Bt,
                                          const float* __restrict__ bias, float scale,
                                          u16* __restrict__ Obf, float* __restrict__ Of,
                                          int m_tile, int n_tile) {
  __shared__ u16 ldsA[128 * 64];
  __shared__ u16 ldsB[128 * 64];
  const int tid = threadIdx.x;
  const int lane = tid & 63, wave = tid >> 6;
  const int wm = wave >> 1, wn = wave & 1;
  const int m0 = m_tile * 128, n0 = n_tile * 128;

  f32x4 acc[4][4] = {};

  const int srow = tid >> 3;                     // 0..31
  const int sslot = (tid & 7) ^ (srow & 7);      // logical k-slot to fetch (pre-swizzled source)
  const u16* ga = A + (size_t)(m0 + srow) * K_ + sslot * 8;
  const u16* gb = Bt + (size_t)(n0 + srow) * K_ + sslot * 8;
  u16* la = ldsA + tid * 8;
  u16* lb = ldsB + tid * 8;

  const int fr = lane & 15;   // fragment row (A: m, B: n)
  const int kg = lane >> 4;   // k-group 0..3

  for (int k0 = 0; k0 < K_; k0 += 64) {
    #pragma unroll
    for (int j = 0; j < 4; j++) gload16(ga + (size_t)(j * 32) * K_ + k0, la + j * 2048);
    #pragma unroll
    for (int j = 0; j < 4; j++) gload16(gb + (size_t)(j * 32) * K_ + k0, lb + j * 2048);
    __syncthreads();

    #pragma unroll
    for (int kk = 0; kk < 2; kk++) {
      const int ps = (((kk << 2) | kg) ^ (fr & 7)) * 8;   // swizzled read
      bf16x8 a[4], b[4];
      #pragma unroll
      for (int mf = 0; mf < 4; mf++)
        a[mf] = *(const bf16x8*)&ldsA[(wm * 64 + mf * 16 + fr) * 64 + ps];
      #pragma unroll
      for (int nf = 0; nf < 4; nf++)
        b[nf] = *(const bf16x8*)&ldsB[(wn * 64 + nf * 16 + fr) * 64 + ps];
      #pragma unroll
      for (int mf = 0; mf < 4; mf++)
        #pragma unroll
        for (int nf = 0; nf < 4; nf++)
          acc[mf][nf] = __builtin_amdgcn_mfma_f32_16x16x32_bf16(a[mf], b[nf], acc[mf][nf], 0, 0, 0);
    }
    __syncthreads();
  }

  float bcol[4];
  #pragma unroll
  for (int nf = 0; nf < 4; nf++) bcol[nf] = bias[n0 + wn * 64 + nf * 16 + fr];

  if (MODE == 2) {
    // V^T store: out[((b*16+h)*64+d)*2048 + s], col=h*64+d, row=b*2048+s.
    #pragma unroll
    for (int mf = 0; mf < 4; mf++) {
      const int row0 = m0 + wm * 64 + mf * 16 + kg * 4;
      #pragma unroll
      for (int nf = 0; nf < 4; nf++) {
        const int col = n0 + wn * 64 + nf * 16 + fr;
        u16x4 o;
        #pragma unroll
        for (int r = 0; r < 4; r++) o[r] = f2bf(acc[mf][nf][r] + bcol[nf]);
        size_t idx = (((size_t)(col + ((row0 >> 11) << 10))) << 11) + (row0 & 2047);
        *(u16x4*)(Obf + idx) = o;
      }
    }
  } else {
    #pragma unroll
    for (int mf = 0; mf < 4; mf++)
      #pragma unroll
      for (int r = 0; r < 4; r++) {
        const int row = m0 + wm * 64 + mf * 16 + kg * 4 + r;
        #pragma unroll
        for (int nf = 0; nf < 4; nf++) {
          const int col = n0 + wn * 64 + nf * 16 + fr;
          float val = (acc[mf][nf][r] + bcol[nf]) * scale;
          if (MODE == 0) Obf[(size_t)row * H_ + col] = f2bf(val);
          else           Of [(size_t)row * H_ + col] = val;
        }
      }
  }
}

__global__ __launch_bounds__(256) void gemm_qkv(const u16* __restrict__ xb, const u16* __restrict__ wt,
                                                const float* __restrict__ b0, const float* __restrict__ b1,
                                                const float* __restrict__ b2,
                                                u16* __restrict__ QKo, u16* __restrict__ VTo) {
  const int z = blockIdx.z;
  const u16* A = xb + (size_t)z * MR_ * K_;
  const u16* Bt = wt + (size_t)z * H_ * K_;
  if (z == 2) {
    gemm_body<2>(A, Bt, b2, 1.0f, VTo, nullptr, blockIdx.y, blockIdx.x);
  } else {
    const float* bias = z == 0 ? b0 : b1;
    const float scale = z == 0 ? 0.125f : 1.0f;   // fold 1/sqrt(HD) into Q
    gemm_body<0>(A, Bt, bias, scale, QKo + (size_t)z * MR_ * H_, nullptr, blockIdx.y, blockIdx.x);
  }
}

__global__ __launch_bounds__(256) void gemm_out(const u16* __restrict__ ctx, const u16* __restrict__ wot,
                                                const float* __restrict__ bo, float* __restrict__ out) {
  gemm_body<1>(ctx, wot, bo, 1.0f, nullptr, out, blockIdx.y, blockIdx.x);
}

// ---------------- flash attention: 4 waves x 16 q-rows, KVBLK=64 ----------------
// K[s][d] and V^T[d][s] tiles double-buffered in LDS (global_load_lds width 16,
// both-sides XOR swizzle). Next tile staged right after the barrier, before compute
// (T3 2-phase: the vmcnt(0) drain at the NEXT barrier overlaps with this tile's compute).
// P staged through per-wave swizzled LDS (wave-synchronous, no extra barrier).
__global__ __launch_bounds__(256) void attn(const u16* __restrict__ qp, const u16* __restrict__ kp,
                                            const u16* __restrict__ vt, u16* __restrict__ ctx) {
  __shared__ u16 Kl[2][64 * 64];     // [s][d-slot], swizzled: phys_slot = slot ^ (s&7)
  __shared__ u16 Vl[2][64 * 64];     // [d][s-slot], swizzled: phys_slot = slot ^ (d&7)
  __shared__ u16 Plds[4][16 * 64];   // per-wave P tile, swizzled
  const int bh = blockIdx.y;
  const int b = bh >> 4, h = bh & 15;
  const int q0 = blockIdx.x * 64;
  const int tid = threadIdx.x;
  const int wave = tid >> 6, lane = tid & 63;
  const int fr = lane & 15, kg = lane >> 4;

  const u16* Q   = qp + (size_t)b * S_ * H_ + h * HD_;
  const u16* Kb  = kp + (size_t)b * S_ * H_ + h * HD_;
  const u16* Vtb = vt + (size_t)bh * HD_ * S_;
  u16* O = ctx + (size_t)b * S_ * H_ + h * HD_;
  u16* Pw = Plds[wave];

  // staging: thread t -> LDS row j*32 + t/8, phys slot t%8 (linear dest = base + t*16B).
  // source fetches logical slot (t%8) ^ (row&7) so LDS[row][phys] holds logical phys^row&7.
  const int srow = tid >> 3;                  // 0..31
  const int sslot = (tid & 7) ^ (srow & 7);   // logical slot to fetch

  const int qrow = q0 + wave * 16 + fr;
  bf16x8 qf[2];
  qf[0] = *(const bf16x8*)&Q[(size_t)qrow * H_ + kg * 8];
  qf[1] = *(const bf16x8*)&Q[(size_t)qrow * H_ + 32 + kg * 8];

  f32x4 oacc[4] = {};
  float mrow[4], lrow[4];
  #pragma unroll
  for (int r = 0; r < 4; r++) { mrow[r] = -1e30f; lrow[r] = 0.f; }

  // prologue: stage tile 0 into buffer 0
  #pragma unroll
  for (int j = 0; j < 2; j++) {
    gload16(Kb + (size_t)(srow + 32 * j) * H_ + sslot * 8, &Kl[0][0] + j * 2048 + tid * 8);
    gload16(Vtb + (size_t)(srow + 32 * j) * S_ + sslot * 8, &Vl[0][0] + j * 2048 + tid * 8);
  }

  for (int it = 0; it < S_ / 64; ++it) {
    const int s0 = it * 64, cur = it & 1;
    __syncthreads();   // staged tile visible (compiler drains vmcnt here)
    if (it + 1 < S_ / 64) {   // issue next tile's loads; drained at NEXT barrier
      #pragma unroll
      for (int j = 0; j < 2; j++) {
        gload16(Kb + (size_t)(s0 + 64 + srow + 32 * j) * H_ + sslot * 8,
                &Kl[cur ^ 1][0] + j * 2048 + tid * 8);
        gload16(Vtb + (size_t)(srow + 32 * j) * S_ + s0 + 64 + sslot * 8,
                &Vl[cur ^ 1][0] + j * 2048 + tid * 8);
      }
    }
    // QK^T: A=Q (regs), B=K^T from LDS. sc[cf]: D[q=kg*4+r][s=cf*16+fr]
    f32x4 sc[4] = {};
    #pragma unroll
    for (int cf = 0; cf < 4; cf++) {
      const int s = cf * 16 + fr;
      #pragma unroll
      for (int kk = 0; kk < 2; kk++) {
        bf16x8 kf = *(const bf16x8*)&Kl[cur][s * 64 + ((((kk << 2) | kg) ^ (fr & 7)) << 3)];
        sc[cf] = __builtin_amdgcn_mfma_f32_16x16x32_bf16(qf[kk], kf, sc[cf], 0, 0, 0);
      }
    }
    // online softmax over s (16-lane fr-group reductions); rows q = kg*4+r
    float tmax[4], psum[4], sf[4], p[4][4];
    #pragma unroll
    for (int r = 0; r < 4; r++)
      tmax[r] = fmaxf(fmaxf(sc[0][r], sc[1][r]), fmaxf(sc[2][r], sc[3][r]));
    #pragma unroll
    for (int off = 1; off < 16; off <<= 1)
      #pragma unroll
      for (int r = 0; r < 4; r++) tmax[r] = fmaxf(tmax[r], __shfl_xor(tmax[r], off, 64));
    #pragma unroll
    for (int r = 0; r < 4; r++) {
      float mn = fmaxf(mrow[r], tmax[r]);
      sf[r] = __expf(mrow[r] - mn);
      mrow[r] = mn;
      float s = 0.f;
      #pragma unroll
      for (int cf = 0; cf < 4; cf++) { p[cf][r] = __expf(sc[cf][r] - mn); s += p[cf][r]; }
      psum[r] = s;
    }
    #pragma unroll
    for (int off = 1; off < 16; off <<= 1)
      #pragma unroll
      for (int r = 0; r < 4; r++) psum[r] += __shfl_xor(psum[r], off, 64);
    #pragma unroll
    for (int r = 0; r < 4; r++) {
      lrow[r] = lrow[r] * sf[r] + psum[r];
      #pragma unroll
      for (int nf = 0; nf < 4; nf++) oacc[nf][r] *= sf[r];
    }
    // write P tile (bf16, swizzled): row q=kg*4+r, col s=cf*16+fr
    #pragma unroll
    for (int r = 0; r < 4; r++) {
      const int prow = kg * 4 + r, sw = prow & 7;
      #pragma unroll
      for (int cf = 0; cf < 4; cf++) {
        const int c = cf * 16 + fr;
        Pw[prow * 64 + (((c >> 3) ^ sw) << 3) + (c & 7)] = f2bf(p[cf][r]);
      }
    }
    // PV: A=P[q][s] from own-wave LDS, B=V^T[d][s] from LDS
    #pragma unroll
    for (int kk = 0; kk < 2; kk++) {
      bf16x8 pf = *(const bf16x8*)&Pw[fr * 64 + ((((kk << 2) | kg) ^ (fr & 7)) << 3)];
      #pragma unroll
      for (int nf = 0; nf < 4; nf++) {
        const int d = nf * 16 + fr;
        bf16x8 vf = *(const bf16x8*)&Vl[cur][d * 64 + ((((kk << 2) | kg) ^ (d & 7)) << 3)];
        oacc[nf] = __builtin_amdgcn_mfma_f32_16x16x32_bf16(pf, vf, oacc[nf], 0, 0, 0);
      }
    }
  }
  // epilogue: O / l -> ctx (bf16)
  float rinv[4];
  #pragma unroll
  for (int r = 0; r < 4; r++) rinv[r] = 1.0f / lrow[r];
  #pragma unroll
  for (int nf = 0; nf < 4; nf++)
    #pragma unroll
    for (int r = 0; r < 4; r++) {
      int row = q0 + wave * 16 + kg * 4 + r;
      O[(size_t)row * H_ + nf * 16 + fr] = f2bf(oacc[nf][r] * rinv[r]);
    }
}

extern "C" void kernel_launch(void* const* d_in, const int* in_sizes, int n_in,
                              void* d_out, int out_size, void* d_ws, size_t ws_size,
                              hipStream_t stream) {
  const float* q  = (const float*)d_in[0];
  const float* k  = (const float*)d_in[1];
  const float* v  = (const float*)d_in[2];
  const float* Wq = (const float*)d_in[3];
  const float* bq = (const float*)d_in[4];
  const float* Wk = (const float*)d_in[5];
  const float* bk = (const float*)d_in[6];
  const float* Wv = (const float*)d_in[7];
  const float* bv = (const float*)d_in[8];
  const float* Wo = (const float*)d_in[9];
  const float* bo = (const float*)d_in[10];
  float* out = (float*)d_out;

  char* ws = (char*)d_ws;
  const size_t MB = 1024 * 1024;
  u16* xb   = (u16*)(ws);             // q,k,v bf16: 3 x 8MB      [0,24)
  u16* wt   = (u16*)(ws + 24 * MB);   // 4 x 2MB transposed W     [24,32)
  u16* qkp  = (u16*)(ws + 32 * MB);   // qp,kp: 2 x 8MB           [32,48)
  u16* vtp  = (u16*)(ws + 48 * MB);   // V^T [bh][d][s]: 8MB      [48,56)
  u16* ctx  = (u16*)(ws);             // reuse xb region after gemm_qkv

  cvt3  <<<dim3(4096, 1, 3), 256, 0, stream>>>(q, k, v, xb);
  wtrans<<<dim3(32, 32, 4),  256, 0, stream>>>(Wq, Wk, Wv, Wo, wt);
  gemm_qkv<<<dim3(8, 32, 3), 256, 0, stream>>>(xb, wt, bq, bk, bv, qkp, vtp);
  attn  <<<dim3(32, 32),     256, 0, stream>>>(qkp, qkp + (size_t)MR_ * H_, vtp, ctx);
  gemm_out<<<dim3(8, 32, 1), 256, 0, stream>>>(ctx, wt + (size_t)3 * H_ * K_, bo, out);
}

// Round 4
// 163.266 us; speedup vs baseline: 1.9227x; 1.2319x over previous
//
#include <hip/hip_runtime.h>

typedef unsigned short u16;
typedef __attribute__((ext_vector_type(8))) short bf16x8;
typedef __attribute__((ext_vector_type(4))) float f32x4;
typedef __attribute__((ext_vector_type(4))) unsigned short u16x4;

#define B_  2
#define S_  2048
#define H_  1024
#define NH_ 16
#define HD_ 64
#define MR_ (B_*S_)   /* 4096 rows */
#define K_  H_

__device__ __forceinline__ u16 f2bf(float f) {
  union { float f; unsigned u; } x; x.f = f;
  unsigned r = x.u + 0x7fffu + ((x.u >> 16) & 1u);
  return (u16)(r >> 16);
}

__device__ __forceinline__ void gload16(const u16* g, u16* l) {
  __builtin_amdgcn_global_load_lds((const __attribute__((address_space(1))) void*)g,
                                   (__attribute__((address_space(3))) void*)l, 16, 0, 0);
}

// ---------------- convert q,k,v f32 -> bf16 ----------------
__global__ __launch_bounds__(256) void cvt3(const float* __restrict__ q, const float* __restrict__ k,
                                            const float* __restrict__ v, u16* __restrict__ dst) {
  const float* src = blockIdx.z == 0 ? q : blockIdx.z == 1 ? k : v;
  u16* d = dst + (size_t)blockIdx.z * MR_ * H_;
  size_t i = ((size_t)blockIdx.x * 256 + threadIdx.x) * 4;
  float4 f = *(const float4*)(src + i);
  u16x4 o = { f2bf(f.x), f2bf(f.y), f2bf(f.z), f2bf(f.w) };
  *(u16x4*)(d + i) = o;
}

// ---------------- transpose + convert weights: Wt[n][k] = bf16(W[k][n]) ----------------
__global__ __launch_bounds__(256) void wtrans(const float* __restrict__ Wq, const float* __restrict__ Wk,
                                              const float* __restrict__ Wv, const float* __restrict__ Wo,
                                              u16* __restrict__ wt) {
  const int z = blockIdx.z;
  const float* W = z == 0 ? Wq : z == 1 ? Wk : z == 2 ? Wv : Wo;
  u16* Wt = wt + (size_t)z * H_ * K_;
  __shared__ float t[32][33];
  const int n0 = blockIdx.x * 32, k0 = blockIdx.y * 32;
  const int tx = threadIdx.x & 31, ty = threadIdx.x >> 5;  // ty 0..7
  #pragma unroll
  for (int i = 0; i < 4; i++) t[ty + 8*i][tx] = W[(size_t)(k0 + ty + 8*i) * H_ + n0 + tx];
  __syncthreads();
  #pragma unroll
  for (int i = 0; i < 4; i++) Wt[(size_t)(n0 + ty + 8*i) * K_ + k0 + tx] = f2bf(t[tx][ty + 8*i]);
}

// ---------------- GEMM body: A[M,K] bf16 row-major, Bt[N,K] bf16 row-major ----------------
// 128x128 tile, BK=64, 256 threads (4 waves, 2x2), mfma_f32_16x16x32_bf16.
// MODE 0: bf16 out row-major (scaled); MODE 1: f32 out; MODE 2: bf16 V^T out [bh][d][s].
template <int MODE>
__device__ __forceinline__ void gemm_body(const u16* __restrict__ A, const u16* __restrict__ Bt,
                                          const float* __restrict__ bias, float scale,
                                          u16* __restrict__ Obf, float* __restrict__ Of,
                                          int m_tile, int n_tile) {
  __shared__ u16 ldsA[128 * 64];
  __shared__ u16 ldsB[128 * 64];
  const int tid = threadIdx.x;
  const int lane = tid & 63, wave = tid >> 6;
  const int wm = wave >> 1, wn = wave & 1;
  const int m0 = m_tile * 128, n0 = n_tile * 128;

  f32x4 acc[4][4] = {};

  const int srow = tid >> 3;                     // 0..31
  const int sslot = (tid & 7) ^ (srow & 7);      // logical k-slot to fetch (pre-swizzled source)
  const u16* ga = A + (size_t)(m0 + srow) * K_ + sslot * 8;
  const u16* gb = Bt + (size_t)(n0 + srow) * K_ + sslot * 8;
  u16* la = ldsA + tid * 8;
  u16* lb = ldsB + tid * 8;

  const int fr = lane & 15;   // fragment row (A: m, B: n)
  const int kg = lane >> 4;   // k-group 0..3

  for (int k0 = 0; k0 < K_; k0 += 64) {
    #pragma unroll
    for (int j = 0; j < 4; j++) gload16(ga + (size_t)(j * 32) * K_ + k0, la + j * 2048);
    #pragma unroll
    for (int j = 0; j < 4; j++) gload16(gb + (size_t)(j * 32) * K_ + k0, lb + j * 2048);
    __syncthreads();

    #pragma unroll
    for (int kk = 0; kk < 2; kk++) {
      const int ps = (((kk << 2) | kg) ^ (fr & 7)) * 8;   // swizzled read
      bf16x8 a[4], b[4];
      #pragma unroll
      for (int mf = 0; mf < 4; mf++)
        a[mf] = *(const bf16x8*)&ldsA[(wm * 64 + mf * 16 + fr) * 64 + ps];
      #pragma unroll
      for (int nf = 0; nf < 4; nf++)
        b[nf] = *(const bf16x8*)&ldsB[(wn * 64 + nf * 16 + fr) * 64 + ps];
      #pragma unroll
      for (int mf = 0; mf < 4; mf++)
        #pragma unroll
        for (int nf = 0; nf < 4; nf++)
          acc[mf][nf] = __builtin_amdgcn_mfma_f32_16x16x32_bf16(a[mf], b[nf], acc[mf][nf], 0, 0, 0);
    }
    __syncthreads();
  }

  float bcol[4];
  #pragma unroll
  for (int nf = 0; nf < 4; nf++) bcol[nf] = bias[n0 + wn * 64 + nf * 16 + fr];

  if (MODE == 2) {
    // V^T store: out[((b*16+h)*64+d)*2048 + s], col=h*64+d, row=b*2048+s.
    #pragma unroll
    for (int mf = 0; mf < 4; mf++) {
      const int row0 = m0 + wm * 64 + mf * 16 + kg * 4;
      #pragma unroll
      for (int nf = 0; nf < 4; nf++) {
        const int col = n0 + wn * 64 + nf * 16 + fr;
        u16x4 o;
        #pragma unroll
        for (int r = 0; r < 4; r++) o[r] = f2bf(acc[mf][nf][r] + bcol[nf]);
        size_t idx = (((size_t)(col + ((row0 >> 11) << 10))) << 11) + (row0 & 2047);
        *(u16x4*)(Obf + idx) = o;
      }
    }
  } else {
    #pragma unroll
    for (int mf = 0; mf < 4; mf++)
      #pragma unroll
      for (int r = 0; r < 4; r++) {
        const int row = m0 + wm * 64 + mf * 16 + kg * 4 + r;
        #pragma unroll
        for (int nf = 0; nf < 4; nf++) {
          const int col = n0 + wn * 64 + nf * 16 + fr;
          float val = (acc[mf][nf][r] + bcol[nf]) * scale;
          if (MODE == 0) Obf[(size_t)row * H_ + col] = f2bf(val);
          else           Of [(size_t)row * H_ + col] = val;
        }
      }
  }
}

__global__ __launch_bounds__(256) void gemm_qkv(const u16* __restrict__ xb, const u16* __restrict__ wt,
                                                const float* __restrict__ b0, const float* __restrict__ b1,
                                                const float* __restrict__ b2,
                                                u16* __restrict__ QKo, u16* __restrict__ VTo) {
  const int z = blockIdx.z;
  const u16* A = xb + (size_t)z * MR_ * K_;
  const u16* Bt = wt + (size_t)z * H_ * K_;
  if (z == 2) {
    gemm_body<2>(A, Bt, b2, 1.0f, VTo, nullptr, blockIdx.y, blockIdx.x);
  } else {
    const float* bias = z == 0 ? b0 : b1;
    // fold 1/sqrt(HD) AND log2(e) into Q so softmax uses raw v_exp_f32 (exp2)
    const float scale = z == 0 ? 0.18033688011112042f : 1.0f;
    gemm_body<0>(A, Bt, bias, scale, QKo + (size_t)z * MR_ * H_, nullptr, blockIdx.y, blockIdx.x);
  }
}

__global__ __launch_bounds__(256) void gemm_out(const u16* __restrict__ ctx, const u16* __restrict__ wot,
                                                const float* __restrict__ bo, float* __restrict__ out) {
  gemm_body<1>(ctx, wot, bo, 1.0f, nullptr, out, blockIdx.y, blockIdx.x);
}

// ---------------- flash attention: 4 waves x 16 q-rows, KVBLK=64 ----------------
// Swapped QK^T: sc = mfma(K, Q) -> lane holds S[s=cf*16+kg*4+r][q=fr]: softmax row
// state (m,l) is per-lane scalar; reduce across kg = 2 shfl_xor; P write = 4 packed
// ds_write_b64. K/V^T double-buffered LDS via global_load_lds + XOR swizzle.
__global__ __launch_bounds__(256) void attn(const u16* __restrict__ qp, const u16* __restrict__ kp,
                                            const u16* __restrict__ vt, u16* __restrict__ ctx) {
  __shared__ u16 Kl[2][64 * 64];     // [s][d-slot], phys_slot = slot ^ (s&7)
  __shared__ u16 Vl[2][64 * 64];     // [d][s-slot], phys_slot = slot ^ (d&7)
  __shared__ u16 Plds[4][16 * 64];   // per-wave P[q][s], phys_slot = slot ^ (q&7)
  const int bh = blockIdx.y;
  const int b = bh >> 4, h = bh & 15;
  const int q0 = blockIdx.x * 64;
  const int tid = threadIdx.x;
  const int wave = tid >> 6, lane = tid & 63;
  const int fr = lane & 15, kg = lane >> 4;

  const u16* Q   = qp + (size_t)b * S_ * H_ + h * HD_;
  const u16* Kb  = kp + (size_t)b * S_ * H_ + h * HD_;
  const u16* Vtb = vt + (size_t)bh * HD_ * S_;
  u16* O = ctx + (size_t)b * S_ * H_ + h * HD_;
  u16* Pw = Plds[wave];

  const int srow = tid >> 3;                  // 0..31
  const int sslot = (tid & 7) ^ (srow & 7);   // logical slot to fetch (pre-swizzled source)

  const int qrow = q0 + wave * 16 + fr;
  bf16x8 qf[2];
  qf[0] = *(const bf16x8*)&Q[(size_t)qrow * H_ + kg * 8];
  qf[1] = *(const bf16x8*)&Q[(size_t)qrow * H_ + 32 + kg * 8];

  f32x4 oacc[4] = {};
  float m_run = -1e30f, l_run = 0.f;   // per-lane: q = fr

  // prologue: stage tile 0 into buffer 0
  #pragma unroll
  for (int j = 0; j < 2; j++) {
    gload16(Kb + (size_t)(srow + 32 * j) * H_ + sslot * 8, &Kl[0][0] + j * 2048 + tid * 8);
    gload16(Vtb + (size_t)(srow + 32 * j) * S_ + sslot * 8, &Vl[0][0] + j * 2048 + tid * 8);
  }

  for (int it = 0; it < S_ / 64; ++it) {
    const int s0 = it * 64, cur = it & 1;
    __syncthreads();   // staged tile visible
    if (it + 1 < S_ / 64) {   // issue next tile's loads; drained at NEXT barrier
      #pragma unroll
      for (int j = 0; j < 2; j++) {
        gload16(Kb + (size_t)(s0 + 64 + srow + 32 * j) * H_ + sslot * 8,
                &Kl[cur ^ 1][0] + j * 2048 + tid * 8);
        gload16(Vtb + (size_t)(srow + 32 * j) * S_ + s0 + 64 + sslot * 8,
                &Vl[cur ^ 1][0] + j * 2048 + tid * 8);
      }
    }
    // swapped QK^T: sc[cf] = K_block * Q -> D[s][q]; lane: s=cf*16+kg*4+r, q=fr
    f32x4 sc[4] = {};
    __builtin_amdgcn_s_setprio(1);
    #pragma unroll
    for (int cf = 0; cf < 4; cf++) {
      const int s = cf * 16 + fr;
      #pragma unroll
      for (int kk = 0; kk < 2; kk++) {
        bf16x8 kf = *(const bf16x8*)&Kl[cur][s * 64 + ((((kk << 2) | kg) ^ (fr & 7)) << 3)];
        sc[cf] = __builtin_amdgcn_mfma_f32_16x16x32_bf16(kf, qf[kk], sc[cf], 0, 0, 0);
      }
    }
    __builtin_amdgcn_s_setprio(0);
    // online softmax, per-lane row q=fr (scores already in log2 units)
    float tmax = sc[0][0];
    #pragma unroll
    for (int cf = 0; cf < 4; cf++)
      #pragma unroll
      for (int r = 0; r < 4; r++) tmax = fmaxf(tmax, sc[cf][r]);
    tmax = fmaxf(tmax, __shfl_xor(tmax, 16, 64));
    tmax = fmaxf(tmax, __shfl_xor(tmax, 32, 64));
    const float mn = fmaxf(m_run, tmax);
    const float sf = __builtin_amdgcn_exp2f(m_run - mn);
    m_run = mn;
    // broadcast sf to PV-row owners: oacc row r corresponds to q = kg*4+r (lane fr=q holds sf)
    float sfq[4];
    const int lbase = lane & 48;
    #pragma unroll
    for (int r = 0; r < 4; r++) sfq[r] = __shfl(sf, lbase | (kg * 4 + r), 64);
    // p = exp2(sc - mn), packed P write (4x ds_write_b64), swizzled like P-read expects
    float psum = 0.f;
    #pragma unroll
    for (int cf = 0; cf < 4; cf++) {
      #pragma unroll
      for (int r = 0; r < 4; r++) { sc[cf][r] = __builtin_amdgcn_exp2f(sc[cf][r] - mn); psum += sc[cf][r]; }
      u16x4 o = { f2bf(sc[cf][0]), f2bf(sc[cf][1]), f2bf(sc[cf][2]), f2bf(sc[cf][3]) };
      const int slot = cf * 2 + (kg >> 1);
      *(u16x4*)&Pw[fr * 64 + ((slot ^ (fr & 7)) << 3) + ((kg & 1) << 2)] = o;
    }
    psum += __shfl_xor(psum, 16, 64);
    psum += __shfl_xor(psum, 32, 64);
    l_run = l_run * sf + psum;
    // rescale existing output
    #pragma unroll
    for (int nf = 0; nf < 4; nf++)
      #pragma unroll
      for (int r = 0; r < 4; r++) oacc[nf][r] *= sfq[r];
    // PV: A=P[q][s] from own-wave LDS, B=V^T[d][s] from LDS
    __builtin_amdgcn_s_setprio(1);
    #pragma unroll
    for (int kk = 0; kk < 2; kk++) {
      bf16x8 pf = *(const bf16x8*)&Pw[fr * 64 + ((((kk << 2) | kg) ^ (fr & 7)) << 3)];
      #pragma unroll
      for (int nf = 0; nf < 4; nf++) {
        const int d = nf * 16 + fr;
        bf16x8 vf = *(const bf16x8*)&Vl[cur][d * 64 + ((((kk << 2) | kg) ^ (d & 7)) << 3)];
        oacc[nf] = __builtin_amdgcn_mfma_f32_16x16x32_bf16(pf, vf, oacc[nf], 0, 0, 0);
      }
    }
    __builtin_amdgcn_s_setprio(0);
  }
  // epilogue: O / l -> ctx (bf16); l for q=kg*4+r lives at lane fr=q
  float lq[4];
  const int lbase = lane & 48;
  #pragma unroll
  for (int r = 0; r < 4; r++) lq[r] = 1.0f / __shfl(l_run, lbase | (kg * 4 + r), 64);
  #pragma unroll
  for (int nf = 0; nf < 4; nf++)
    #pragma unroll
    for (int r = 0; r < 4; r++) {
      int row = q0 + wave * 16 + kg * 4 + r;
      O[(size_t)row * H_ + nf * 16 + fr] = f2bf(oacc[nf][r] * lq[r]);
    }
}

extern "C" void kernel_launch(void* const* d_in, const int* in_sizes, int n_in,
                              void* d_out, int out_size, void* d_ws, size_t ws_size,
                              hipStream_t stream) {
  const float* q  = (const float*)d_in[0];
  const float* k  = (const float*)d_in[1];
  const float* v  = (const float*)d_in[2];
  const float* Wq = (const float*)d_in[3];
  const float* bq = (const float*)d_in[4];
  const float* Wk = (const float*)d_in[5];
  const float* bk = (const float*)d_in[6];
  const float* Wv = (const float*)d_in[7];
  const float* bv = (const float*)d_in[8];
  const float* Wo = (const float*)d_in[9];
  const float* bo = (const float*)d_in[10];
  float* out = (float*)d_out;

  char* ws = (char*)d_ws;
  const size_t MB = 1024 * 1024;
  u16* xb   = (u16*)(ws);             // q,k,v bf16: 3 x 8MB      [0,24)
  u16* wt   = (u16*)(ws + 24 * MB);   // 4 x 2MB transposed W     [24,32)
  u16* qkp  = (u16*)(ws + 32 * MB);   // qp,kp: 2 x 8MB           [32,48)
  u16* vtp  = (u16*)(ws + 48 * MB);   // V^T [bh][d][s]: 8MB      [48,56)
  u16* ctx  = (u16*)(ws);             // reuse xb region after gemm_qkv

  cvt3  <<<dim3(4096, 1, 3), 256, 0, stream>>>(q, k, v, xb);
  wtrans<<<dim3(32, 32, 4),  256, 0, stream>>>(Wq, Wk, Wv, Wo, wt);
  gemm_qkv<<<dim3(8, 32, 3), 256, 0, stream>>>(xb, wt, bq, bk, bv, qkp, vtp);
  attn  <<<dim3(32, 32),     256, 0, stream>>>(qkp, qkp + (size_t)MR_ * H_, vtp, ctx);
  gemm_out<<<dim3(8, 32, 1), 256, 0, stream>>>(ctx, wt + (size_t)3 * H_ * K_, bo, out);
}

// Round 5
// 156.732 us; speedup vs baseline: 2.0029x; 1.0417x over previous
//
#include <hip/hip_runtime.h>

typedef unsigned short u16;
typedef __attribute__((ext_vector_type(8))) short bf16x8;
typedef __attribute__((ext_vector_type(4))) float f32x4;
typedef __attribute__((ext_vector_type(4))) unsigned short u16x4;

#define B_  2
#define S_  2048
#define H_  1024
#define NH_ 16
#define HD_ 64
#define MR_ (B_*S_)   /* 4096 rows */
#define K_  H_

__device__ __forceinline__ u16 f2bf(float f) {
  union { float f; unsigned u; } x; x.f = f;
  unsigned r = x.u + 0x7fffu + ((x.u >> 16) & 1u);
  return (u16)(r >> 16);
}

// packed f32x2 -> bf16x2 (RNE), single VALU op (learn_hip m214v22; no builtin on gfx950)
__device__ __forceinline__ unsigned cvtpk(float lo, float hi) {
  unsigned r;
  asm("v_cvt_pk_bf16_f32 %0, %1, %2" : "=v"(r) : "v"(lo), "v"(hi));
  return r;
}

__device__ __forceinline__ void gload16(const u16* g, u16* l) {
  __builtin_amdgcn_global_load_lds((const __attribute__((address_space(1))) void*)g,
                                   (__attribute__((address_space(3))) void*)l, 16, 0, 0);
}

// ---------------- convert q,k,v f32 -> bf16 ----------------
__global__ __launch_bounds__(256) void cvt3(const float* __restrict__ q, const float* __restrict__ k,
                                            const float* __restrict__ v, u16* __restrict__ dst) {
  const float* src = blockIdx.z == 0 ? q : blockIdx.z == 1 ? k : v;
  u16* d = dst + (size_t)blockIdx.z * MR_ * H_;
  size_t i = ((size_t)blockIdx.x * 256 + threadIdx.x) * 4;
  float4 f = *(const float4*)(src + i);
  u16x4 o = { f2bf(f.x), f2bf(f.y), f2bf(f.z), f2bf(f.w) };
  *(u16x4*)(d + i) = o;
}

// ---------------- transpose + convert weights: Wt[n][k] = bf16(W[k][n]) ----------------
__global__ __launch_bounds__(256) void wtrans(const float* __restrict__ Wq, const float* __restrict__ Wk,
                                              const float* __restrict__ Wv, const float* __restrict__ Wo,
                                              u16* __restrict__ wt) {
  const int z = blockIdx.z;
  const float* W = z == 0 ? Wq : z == 1 ? Wk : z == 2 ? Wv : Wo;
  u16* Wt = wt + (size_t)z * H_ * K_;
  __shared__ float t[32][33];
  const int n0 = blockIdx.x * 32, k0 = blockIdx.y * 32;
  const int tx = threadIdx.x & 31, ty = threadIdx.x >> 5;  // ty 0..7
  #pragma unroll
  for (int i = 0; i < 4; i++) t[ty + 8*i][tx] = W[(size_t)(k0 + ty + 8*i) * H_ + n0 + tx];
  __syncthreads();
  #pragma unroll
  for (int i = 0; i < 4; i++) Wt[(size_t)(n0 + ty + 8*i) * K_ + k0 + tx] = f2bf(t[tx][ty + 8*i]);
}

// ---------------- GEMM body: A[M,K] bf16 row-major, Bt[N,K] bf16 row-major ----------------
// 128x128 tile, BK=64, 256 threads (4 waves, 2x2), mfma_f32_16x16x32_bf16.
// MODE 0: bf16 out row-major (scaled); MODE 1: f32 out; MODE 2: bf16 V^T out [bh][d][s].
template <int MODE>
__device__ __forceinline__ void gemm_body(const u16* __restrict__ A, const u16* __restrict__ Bt,
                                          const float* __restrict__ bias, float scale,
                                          u16* __restrict__ Obf, float* __restrict__ Of,
                                          int m_tile, int n_tile) {
  __shared__ u16 ldsA[128 * 64];
  __shared__ u16 ldsB[128 * 64];
  const int tid = threadIdx.x;
  const int lane = tid & 63, wave = tid >> 6;
  const int wm = wave >> 1, wn = wave & 1;
  const int m0 = m_tile * 128, n0 = n_tile * 128;

  f32x4 acc[4][4] = {};

  const int srow = tid >> 3;                     // 0..31
  const int sslot = (tid & 7) ^ (srow & 7);      // logical k-slot to fetch (pre-swizzled source)
  const u16* ga = A + (size_t)(m0 + srow) * K_ + sslot * 8;
  const u16* gb = Bt + (size_t)(n0 + srow) * K_ + sslot * 8;
  u16* la = ldsA + tid * 8;
  u16* lb = ldsB + tid * 8;

  const int fr = lane & 15;   // fragment row (A: m, B: n)
  const int kg = lane >> 4;   // k-group 0..3

  for (int k0 = 0; k0 < K_; k0 += 64) {
    #pragma unroll
    for (int j = 0; j < 4; j++) gload16(ga + (size_t)(j * 32) * K_ + k0, la + j * 2048);
    #pragma unroll
    for (int j = 0; j < 4; j++) gload16(gb + (size_t)(j * 32) * K_ + k0, lb + j * 2048);
    __syncthreads();

    #pragma unroll
    for (int kk = 0; kk < 2; kk++) {
      const int ps = (((kk << 2) | kg) ^ (fr & 7)) * 8;   // swizzled read
      bf16x8 a[4], b[4];
      #pragma unroll
      for (int mf = 0; mf < 4; mf++)
        a[mf] = *(const bf16x8*)&ldsA[(wm * 64 + mf * 16 + fr) * 64 + ps];
      #pragma unroll
      for (int nf = 0; nf < 4; nf++)
        b[nf] = *(const bf16x8*)&ldsB[(wn * 64 + nf * 16 + fr) * 64 + ps];
      #pragma unroll
      for (int mf = 0; mf < 4; mf++)
        #pragma unroll
        for (int nf = 0; nf < 4; nf++)
          acc[mf][nf] = __builtin_amdgcn_mfma_f32_16x16x32_bf16(a[mf], b[nf], acc[mf][nf], 0, 0, 0);
    }
    __syncthreads();
  }

  float bcol[4];
  #pragma unroll
  for (int nf = 0; nf < 4; nf++) bcol[nf] = bias[n0 + wn * 64 + nf * 16 + fr];

  if (MODE == 2) {
    // V^T store: out[((b*16+h)*64+d)*2048 + s], col=h*64+d, row=b*2048+s.
    #pragma unroll
    for (int mf = 0; mf < 4; mf++) {
      const int row0 = m0 + wm * 64 + mf * 16 + kg * 4;
      #pragma unroll
      for (int nf = 0; nf < 4; nf++) {
        const int col = n0 + wn * 64 + nf * 16 + fr;
        u16x4 o;
        #pragma unroll
        for (int r = 0; r < 4; r++) o[r] = f2bf(acc[mf][nf][r] + bcol[nf]);
        size_t idx = (((size_t)(col + ((row0 >> 11) << 10))) << 11) + (row0 & 2047);
        *(u16x4*)(Obf + idx) = o;
      }
    }
  } else {
    #pragma unroll
    for (int mf = 0; mf < 4; mf++)
      #pragma unroll
      for (int r = 0; r < 4; r++) {
        const int row = m0 + wm * 64 + mf * 16 + kg * 4 + r;
        #pragma unroll
        for (int nf = 0; nf < 4; nf++) {
          const int col = n0 + wn * 64 + nf * 16 + fr;
          float val = (acc[mf][nf][r] + bcol[nf]) * scale;
          if (MODE == 0) Obf[(size_t)row * H_ + col] = f2bf(val);
          else           Of [(size_t)row * H_ + col] = val;
        }
      }
  }
}

__global__ __launch_bounds__(256) void gemm_qkv(const u16* __restrict__ xb, const u16* __restrict__ wt,
                                                const float* __restrict__ b0, const float* __restrict__ b1,
                                                const float* __restrict__ b2,
                                                u16* __restrict__ QKo, u16* __restrict__ VTo) {
  const int z = blockIdx.z;
  const u16* A = xb + (size_t)z * MR_ * K_;
  const u16* Bt = wt + (size_t)z * H_ * K_;
  if (z == 2) {
    gemm_body<2>(A, Bt, b2, 1.0f, VTo, nullptr, blockIdx.y, blockIdx.x);
  } else {
    const float* bias = z == 0 ? b0 : b1;
    // fold 1/sqrt(HD) AND log2(e) into Q so softmax uses raw v_exp_f32 (exp2)
    const float scale = z == 0 ? 0.18033688011112042f : 1.0f;
    gemm_body<0>(A, Bt, bias, scale, QKo + (size_t)z * MR_ * H_, nullptr, blockIdx.y, blockIdx.x);
  }
}

__global__ __launch_bounds__(256) void gemm_out(const u16* __restrict__ ctx, const u16* __restrict__ wot,
                                                const float* __restrict__ bo, float* __restrict__ out) {
  gemm_body<1>(ctx, wot, bo, 1.0f, nullptr, out, blockIdx.y, blockIdx.x);
}

// ---------------- flash attention: 4 waves x 16 q-rows, KVBLK=64 ----------------
// Swapped QK^T (lane holds S[s][q=fr]); per-lane scalar softmax state; defer-max
// (THR=8 in log2 units) skips rescale on ~90% of tiles; cvt_pk packs P to bf16.
__global__ __launch_bounds__(256) void attn(const u16* __restrict__ qp, const u16* __restrict__ kp,
                                            const u16* __restrict__ vt, u16* __restrict__ ctx) {
  __shared__ u16 Kl[2][64 * 64];     // [s][d-slot], phys_slot = slot ^ (s&7)
  __shared__ u16 Vl[2][64 * 64];     // [d][s-slot], phys_slot = slot ^ (d&7)
  __shared__ u16 Plds[4][16 * 64];   // per-wave P[q][s], phys_slot = slot ^ (q&7)
  const int bh = blockIdx.y;
  const int b = bh >> 4, h = bh & 15;
  const int q0 = blockIdx.x * 64;
  const int tid = threadIdx.x;
  const int wave = tid >> 6, lane = tid & 63;
  const int fr = lane & 15, kg = lane >> 4;

  const u16* Q   = qp + (size_t)b * S_ * H_ + h * HD_;
  const u16* Kb  = kp + (size_t)b * S_ * H_ + h * HD_;
  const u16* Vtb = vt + (size_t)bh * HD_ * S_;
  u16* O = ctx + (size_t)b * S_ * H_ + h * HD_;
  u16* Pw = Plds[wave];

  const int srow = tid >> 3;                  // 0..31
  const int sslot = (tid & 7) ^ (srow & 7);   // logical slot to fetch (pre-swizzled source)

  const int qrow = q0 + wave * 16 + fr;
  bf16x8 qf[2];
  qf[0] = *(const bf16x8*)&Q[(size_t)qrow * H_ + kg * 8];
  qf[1] = *(const bf16x8*)&Q[(size_t)qrow * H_ + 32 + kg * 8];

  f32x4 oacc[4] = {};
  float m_run = -1e30f, l_run = 0.f;   // per-lane: q = fr

  // prologue: stage tile 0 into buffer 0
  #pragma unroll
  for (int j = 0; j < 2; j++) {
    gload16(Kb + (size_t)(srow + 32 * j) * H_ + sslot * 8, &Kl[0][0] + j * 2048 + tid * 8);
    gload16(Vtb + (size_t)(srow + 32 * j) * S_ + sslot * 8, &Vl[0][0] + j * 2048 + tid * 8);
  }

  for (int it = 0; it < S_ / 64; ++it) {
    const int s0 = it * 64, cur = it & 1;
    __syncthreads();   // staged tile visible
    if (it + 1 < S_ / 64) {   // issue next tile's loads; drained at NEXT barrier
      #pragma unroll
      for (int j = 0; j < 2; j++) {
        gload16(Kb + (size_t)(s0 + 64 + srow + 32 * j) * H_ + sslot * 8,
                &Kl[cur ^ 1][0] + j * 2048 + tid * 8);
        gload16(Vtb + (size_t)(srow + 32 * j) * S_ + s0 + 64 + sslot * 8,
                &Vl[cur ^ 1][0] + j * 2048 + tid * 8);
      }
    }
    // swapped QK^T: sc[cf] = K_block * Q -> D[s][q]; lane: s=cf*16+kg*4+r, q=fr
    f32x4 sc[4] = {};
    __builtin_amdgcn_s_setprio(1);
    #pragma unroll
    for (int cf = 0; cf < 4; cf++) {
      const int s = cf * 16 + fr;
      #pragma unroll
      for (int kk = 0; kk < 2; kk++) {
        bf16x8 kf = *(const bf16x8*)&Kl[cur][s * 64 + ((((kk << 2) | kg) ^ (fr & 7)) << 3)];
        sc[cf] = __builtin_amdgcn_mfma_f32_16x16x32_bf16(kf, qf[kk], sc[cf], 0, 0, 0);
      }
    }
    __builtin_amdgcn_s_setprio(0);
    // tree max (depth 4, max3-fusable)
    float m4[4];
    #pragma unroll
    for (int r = 0; r < 4; r++)
      m4[r] = fmaxf(fmaxf(sc[0][r], sc[1][r]), fmaxf(sc[2][r], sc[3][r]));
    float tmax = fmaxf(fmaxf(m4[0], m4[1]), fmaxf(m4[2], m4[3]));
    tmax = fmaxf(tmax, __shfl_xor(tmax, 16, 64));
    tmax = fmaxf(tmax, __shfl_xor(tmax, 32, 64));
    // defer-max: only rescale when the running max grew by >8 (log2 units) on some lane
    if (!__all(tmax <= m_run + 8.0f)) {
      const float mn = fmaxf(m_run, tmax);
      const float sf = __builtin_amdgcn_exp2f(m_run - mn);
      m_run = mn;
      float sfq[4];
      const int lbase = lane & 48;
      #pragma unroll
      for (int r = 0; r < 4; r++) sfq[r] = __shfl(sf, lbase | (kg * 4 + r), 64);
      #pragma unroll
      for (int nf = 0; nf < 4; nf++)
        #pragma unroll
        for (int r = 0; r < 4; r++) oacc[nf][r] *= sfq[r];
      l_run *= sf;
    }
    // p = exp2(sc - m_run) (bounded by 2^8), packed cvt_pk P write (uint2 = ds_write_b64)
    float psum = 0.f;
    #pragma unroll
    for (int cf = 0; cf < 4; cf++) {
      #pragma unroll
      for (int r = 0; r < 4; r++) { sc[cf][r] = __builtin_amdgcn_exp2f(sc[cf][r] - m_run); psum += sc[cf][r]; }
      uint2 o = { cvtpk(sc[cf][0], sc[cf][1]), cvtpk(sc[cf][2], sc[cf][3]) };
      const int slot = cf * 2 + (kg >> 1);
      *(uint2*)&Pw[fr * 64 + ((slot ^ (fr & 7)) << 3) + ((kg & 1) << 2)] = o;
    }
    psum += __shfl_xor(psum, 16, 64);
    psum += __shfl_xor(psum, 32, 64);
    l_run += psum;
    // PV: A=P[q][s] from own-wave LDS, B=V^T[d][s] from LDS
    __builtin_amdgcn_s_setprio(1);
    #pragma unroll
    for (int kk = 0; kk < 2; kk++) {
      bf16x8 pf = *(const bf16x8*)&Pw[fr * 64 + ((((kk << 2) | kg) ^ (fr & 7)) << 3)];
      #pragma unroll
      for (int nf = 0; nf < 4; nf++) {
        const int d = nf * 16 + fr;
        bf16x8 vf = *(const bf16x8*)&Vl[cur][d * 64 + ((((kk << 2) | kg) ^ (d & 7)) << 3)];
        oacc[nf] = __builtin_amdgcn_mfma_f32_16x16x32_bf16(pf, vf, oacc[nf], 0, 0, 0);
      }
    }
    __builtin_amdgcn_s_setprio(0);
  }
  // epilogue: O / l -> ctx (bf16); l for q=kg*4+r lives at lane fr=q
  float lq[4];
  const int lbase = lane & 48;
  #pragma unroll
  for (int r = 0; r < 4; r++) lq[r] = 1.0f / __shfl(l_run, lbase | (kg * 4 + r), 64);
  #pragma unroll
  for (int nf = 0; nf < 4; nf++)
    #pragma unroll
    for (int r = 0; r < 4; r++) {
      int row = q0 + wave * 16 + kg * 4 + r;
      O[(size_t)row * H_ + nf * 16 + fr] = f2bf(oacc[nf][r] * lq[r]);
    }
}

extern "C" void kernel_launch(void* const* d_in, const int* in_sizes, int n_in,
                              void* d_out, int out_size, void* d_ws, size_t ws_size,
                              hipStream_t stream) {
  const float* q  = (const float*)d_in[0];
  const float* k  = (const float*)d_in[1];
  const float* v  = (const float*)d_in[2];
  const float* Wq = (const float*)d_in[3];
  const float* bq = (const float*)d_in[4];
  const float* Wk = (const float*)d_in[5];
  const float* bk = (const float*)d_in[6];
  const float* Wv = (const float*)d_in[7];
  const float* bv = (const float*)d_in[8];
  const float* Wo = (const float*)d_in[9];
  const float* bo = (const float*)d_in[10];
  float* out = (float*)d_out;

  char* ws = (char*)d_ws;
  const size_t MB = 1024 * 1024;
  u16* xb   = (u16*)(ws);             // q,k,v bf16: 3 x 8MB      [0,24)
  u16* wt   = (u16*)(ws + 24 * MB);   // 4 x 2MB transposed W     [24,32)
  u16* qkp  = (u16*)(ws + 32 * MB);   // qp,kp: 2 x 8MB           [32,48)
  u16* vtp  = (u16*)(ws + 48 * MB);   // V^T [bh][d][s]: 8MB      [48,56)
  u16* ctx  = (u16*)(ws);             // reuse xb region after gemm_qkv

  cvt3  <<<dim3(4096, 1, 3), 256, 0, stream>>>(q, k, v, xb);
  wtrans<<<dim3(32, 32, 4),  256, 0, stream>>>(Wq, Wk, Wv, Wo, wt);
  gemm_qkv<<<dim3(8, 32, 3), 256, 0, stream>>>(xb, wt, bq, bk, bv, qkp, vtp);
  attn  <<<dim3(32, 32),     256, 0, stream>>>(qkp, qkp + (size_t)MR_ * H_, vtp, ctx);
  gemm_out<<<dim3(8, 32, 1), 256, 0, stream>>>(ctx, wt + (size_t)3 * H_ * K_, bo, out);
}

// Round 6
// 153.569 us; speedup vs baseline: 2.0441x; 1.0206x over previous
//
#include <hip/hip_runtime.h>

typedef unsigned short u16;
typedef __attribute__((ext_vector_type(8))) short bf16x8;
typedef __attribute__((ext_vector_type(4))) float f32x4;
typedef __attribute__((ext_vector_type(16))) float f32x16;
typedef __attribute__((ext_vector_type(4))) unsigned short u16x4;
typedef __attribute__((ext_vector_type(4))) unsigned int u32x4;

#define B_  2
#define S_  2048
#define H_  1024
#define NH_ 16
#define HD_ 64
#define MR_ (B_*S_)   /* 4096 rows */
#define K_  H_

__device__ __forceinline__ u16 f2bf(float f) {
  union { float f; unsigned u; } x; x.f = f;
  unsigned r = x.u + 0x7fffu + ((x.u >> 16) & 1u);
  return (u16)(r >> 16);
}

// packed f32x2 -> bf16x2 (RNE), single VALU op (no builtin on gfx950)
__device__ __forceinline__ unsigned cvtpk(float lo, float hi) {
  unsigned r;
  asm("v_cvt_pk_bf16_f32 %0, %1, %2" : "=v"(r) : "v"(lo), "v"(hi));
  return r;
}

__device__ __forceinline__ void gload16(const u16* g, u16* l) {
  __builtin_amdgcn_global_load_lds((const __attribute__((address_space(1))) void*)g,
                                   (__attribute__((address_space(3))) void*)l, 16, 0, 0);
}

// ---------------- convert q,k,v f32 -> bf16 ----------------
__global__ __launch_bounds__(256) void cvt3(const float* __restrict__ q, const float* __restrict__ k,
                                            const float* __restrict__ v, u16* __restrict__ dst) {
  const float* src = blockIdx.z == 0 ? q : blockIdx.z == 1 ? k : v;
  u16* d = dst + (size_t)blockIdx.z * MR_ * H_;
  size_t i = ((size_t)blockIdx.x * 256 + threadIdx.x) * 4;
  float4 f = *(const float4*)(src + i);
  u16x4 o = { f2bf(f.x), f2bf(f.y), f2bf(f.z), f2bf(f.w) };
  *(u16x4*)(d + i) = o;
}

// ---------------- transpose + convert weights: Wt[n][k] = bf16(W[k][n]) ----------------
__global__ __launch_bounds__(256) void wtrans(const float* __restrict__ Wq, const float* __restrict__ Wk,
                                              const float* __restrict__ Wv, const float* __restrict__ Wo,
                                              u16* __restrict__ wt) {
  const int z = blockIdx.z;
  const float* W = z == 0 ? Wq : z == 1 ? Wk : z == 2 ? Wv : Wo;
  u16* Wt = wt + (size_t)z * H_ * K_;
  __shared__ float t[32][33];
  const int n0 = blockIdx.x * 32, k0 = blockIdx.y * 32;
  const int tx = threadIdx.x & 31, ty = threadIdx.x >> 5;  // ty 0..7
  #pragma unroll
  for (int i = 0; i < 4; i++) t[ty + 8*i][tx] = W[(size_t)(k0 + ty + 8*i) * H_ + n0 + tx];
  __syncthreads();
  #pragma unroll
  for (int i = 0; i < 4; i++) Wt[(size_t)(n0 + ty + 8*i) * K_ + k0 + tx] = f2bf(t[tx][ty + 8*i]);
}

// ---------------- GEMM body: A[M,K] bf16 row-major, Bt[N,K] bf16 row-major ----------------
template <int MODE>
__device__ __forceinline__ void gemm_body(const u16* __restrict__ A, const u16* __restrict__ Bt,
                                          const float* __restrict__ bias, float scale,
                                          u16* __restrict__ Obf, float* __restrict__ Of,
                                          int m_tile, int n_tile) {
  __shared__ u16 ldsA[128 * 64];
  __shared__ u16 ldsB[128 * 64];
  const int tid = threadIdx.x;
  const int lane = tid & 63, wave = tid >> 6;
  const int wm = wave >> 1, wn = wave & 1;
  const int m0 = m_tile * 128, n0 = n_tile * 128;

  f32x4 acc[4][4] = {};

  const int srow = tid >> 3;                     // 0..31
  const int sslot = (tid & 7) ^ (srow & 7);      // logical k-slot to fetch (pre-swizzled source)
  const u16* ga = A + (size_t)(m0 + srow) * K_ + sslot * 8;
  const u16* gb = Bt + (size_t)(n0 + srow) * K_ + sslot * 8;
  u16* la = ldsA + tid * 8;
  u16* lb = ldsB + tid * 8;

  const int fr = lane & 15;   // fragment row (A: m, B: n)
  const int kg = lane >> 4;   // k-group 0..3

  for (int k0 = 0; k0 < K_; k0 += 64) {
    #pragma unroll
    for (int j = 0; j < 4; j++) gload16(ga + (size_t)(j * 32) * K_ + k0, la + j * 2048);
    #pragma unroll
    for (int j = 0; j < 4; j++) gload16(gb + (size_t)(j * 32) * K_ + k0, lb + j * 2048);
    __syncthreads();

    #pragma unroll
    for (int kk = 0; kk < 2; kk++) {
      const int ps = (((kk << 2) | kg) ^ (fr & 7)) * 8;   // swizzled read
      bf16x8 a[4], b[4];
      #pragma unroll
      for (int mf = 0; mf < 4; mf++)
        a[mf] = *(const bf16x8*)&ldsA[(wm * 64 + mf * 16 + fr) * 64 + ps];
      #pragma unroll
      for (int nf = 0; nf < 4; nf++)
        b[nf] = *(const bf16x8*)&ldsB[(wn * 64 + nf * 16 + fr) * 64 + ps];
      #pragma unroll
      for (int mf = 0; mf < 4; mf++)
        #pragma unroll
        for (int nf = 0; nf < 4; nf++)
          acc[mf][nf] = __builtin_amdgcn_mfma_f32_16x16x32_bf16(a[mf], b[nf], acc[mf][nf], 0, 0, 0);
    }
    __syncthreads();
  }

  float bcol[4];
  #pragma unroll
  for (int nf = 0; nf < 4; nf++) bcol[nf] = bias[n0 + wn * 64 + nf * 16 + fr];

  if (MODE == 2) {
    // V^T store: out[((b*16+h)*64+d)*2048 + s], col=h*64+d, row=b*2048+s.
    #pragma unroll
    for (int mf = 0; mf < 4; mf++) {
      const int row0 = m0 + wm * 64 + mf * 16 + kg * 4;
      #pragma unroll
      for (int nf = 0; nf < 4; nf++) {
        const int col = n0 + wn * 64 + nf * 16 + fr;
        u16x4 o;
        #pragma unroll
        for (int r = 0; r < 4; r++) o[r] = f2bf(acc[mf][nf][r] + bcol[nf]);
        size_t idx = (((size_t)(col + ((row0 >> 11) << 10))) << 11) + (row0 & 2047);
        *(u16x4*)(Obf + idx) = o;
      }
    }
  } else {
    #pragma unroll
    for (int mf = 0; mf < 4; mf++)
      #pragma unroll
      for (int r = 0; r < 4; r++) {
        const int row = m0 + wm * 64 + mf * 16 + kg * 4 + r;
        #pragma unroll
        for (int nf = 0; nf < 4; nf++) {
          const int col = n0 + wn * 64 + nf * 16 + fr;
          float val = (acc[mf][nf][r] + bcol[nf]) * scale;
          if (MODE == 0) Obf[(size_t)row * H_ + col] = f2bf(val);
          else           Of [(size_t)row * H_ + col] = val;
        }
      }
  }
}

__global__ __launch_bounds__(256) void gemm_qkv(const u16* __restrict__ xb, const u16* __restrict__ wt,
                                                const float* __restrict__ b0, const float* __restrict__ b1,
                                                const float* __restrict__ b2,
                                                u16* __restrict__ QKo, u16* __restrict__ VTo) {
  const int z = blockIdx.z;
  const u16* A = xb + (size_t)z * MR_ * K_;
  const u16* Bt = wt + (size_t)z * H_ * K_;
  if (z == 2) {
    gemm_body<2>(A, Bt, b2, 1.0f, VTo, nullptr, blockIdx.y, blockIdx.x);
  } else {
    const float* bias = z == 0 ? b0 : b1;
    // fold 1/sqrt(HD) AND log2(e) into Q so softmax uses raw v_exp_f32 (exp2)
    const float scale = z == 0 ? 0.18033688011112042f : 1.0f;
    gemm_body<0>(A, Bt, bias, scale, QKo + (size_t)z * MR_ * H_, nullptr, blockIdx.y, blockIdx.x);
  }
}

__global__ __launch_bounds__(256) void gemm_out(const u16* __restrict__ ctx, const u16* __restrict__ wot,
                                                const float* __restrict__ bo, float* __restrict__ out) {
  gemm_body<1>(ctx, wot, bo, 1.0f, nullptr, out, blockIdx.y, blockIdx.x);
}

// ---------------- flash attention: 4 waves x 32 q-rows (32x32 MFMA), KVBLK=64 ----------------
// Swapped QK^T with mfma_32x32x16: lane owns q-col (l&31); all 64 s-scores live on the
// lane pair {l, l^32}. Softmax: in-register tree + ONE shfl_xor(32). P stays in registers:
// cvt_pk packs + one uint2 shfl_xor(32) per ks assemble PV A-fragments (no P-LDS).
__global__ __launch_bounds__(256) void attn(const u16* __restrict__ qp, const u16* __restrict__ kp,
                                            const u16* __restrict__ vt, u16* __restrict__ ctx) {
  __shared__ u16 Kl[2][64 * 64];     // [s][d-slot], phys_slot = slot ^ (s&7)
  __shared__ u16 Vl[2][64 * 64];     // [d][s-slot], phys_slot = slot ^ (d&7)
  const int bh = blockIdx.y;
  const int b = bh >> 4, h = bh & 15;
  const int q0 = blockIdx.x * 128;
  const int tid = threadIdx.x;
  const int w = tid >> 6, l = tid & 63;
  const int ql = l & 31, hi = l >> 5;

  const u16* Q   = qp + (size_t)b * S_ * H_ + h * HD_;
  const u16* Kb  = kp + (size_t)b * S_ * H_ + h * HD_;
  const u16* Vtb = vt + (size_t)bh * HD_ * S_;
  u16* O = ctx + (size_t)b * S_ * H_ + h * HD_;

  const int srow = tid >> 3;                  // 0..31
  const int sslot = (tid & 7) ^ (srow & 7);   // logical slot to fetch (pre-swizzled source)

  // Q B-fragments (loop-invariant): lane holds Q[q=q0+w*32+ql][d = ds*16 + hi*8 + j]
  const int qrow = q0 + w * 32 + ql;
  bf16x8 qf[4];
  #pragma unroll
  for (int ds = 0; ds < 4; ds++)
    qf[ds] = *(const bf16x8*)&Q[(size_t)qrow * H_ + ds * 16 + hi * 8];

  f32x16 oacc0 = {}, oacc1 = {};       // C[q][d], dt=0,1 ; rows q=(r&3)+8*(r>>2)+4*hi, col d=dt*32+ql
  float m_run = -1e30f, l_run = 0.f;   // state for q-col = ql (mirrored on lane pair)

  // prologue: stage tile 0 into buffer 0
  #pragma unroll
  for (int j = 0; j < 2; j++) {
    gload16(Kb + (size_t)(srow + 32 * j) * H_ + sslot * 8, &Kl[0][0] + j * 2048 + tid * 8);
    gload16(Vtb + (size_t)(srow + 32 * j) * S_ + sslot * 8, &Vl[0][0] + j * 2048 + tid * 8);
  }

  for (int it = 0; it < S_ / 64; ++it) {
    const int s0 = it * 64, cur = it & 1;
    __syncthreads();   // staged tile visible
    if (it + 1 < S_ / 64) {
      #pragma unroll
      for (int j = 0; j < 2; j++) {
        gload16(Kb + (size_t)(s0 + 64 + srow + 32 * j) * H_ + sslot * 8,
                &Kl[cur ^ 1][0] + j * 2048 + tid * 8);
        gload16(Vtb + (size_t)(srow + 32 * j) * S_ + s0 + 64 + sslot * 8,
                &Vl[cur ^ 1][0] + j * 2048 + tid * 8);
      }
    }
    // swapped QK^T: sc_st = mfma32(K_frag, Q_frag). D[s][q]: q=l&31, s=st*32+(r&3)+8*(r>>2)+4*hi
    f32x16 sc0 = {}, sc1 = {};
    __builtin_amdgcn_s_setprio(1);
    #pragma unroll
    for (int ds = 0; ds < 4; ds++) {
      const int sl = ((ds * 2 + hi) ^ (ql & 7)) << 3;
      bf16x8 k0 = *(const bf16x8*)&Kl[cur][ql * 64 + sl];
      bf16x8 k1 = *(const bf16x8*)&Kl[cur][(32 + ql) * 64 + sl];
      sc0 = __builtin_amdgcn_mfma_f32_32x32x16_bf16(k0, qf[ds], sc0, 0, 0, 0);
      sc1 = __builtin_amdgcn_mfma_f32_32x32x16_bf16(k1, qf[ds], sc1, 0, 0, 0);
    }
    __builtin_amdgcn_s_setprio(0);
    // tree max over 32 in-register scores, then one cross-half reduce
    float t4[8];
    #pragma unroll
    for (int g = 0; g < 4; g++) {
      t4[g]     = fmaxf(fmaxf(sc0[4*g], sc0[4*g+1]), fmaxf(sc0[4*g+2], sc0[4*g+3]));
      t4[4 + g] = fmaxf(fmaxf(sc1[4*g], sc1[4*g+1]), fmaxf(sc1[4*g+2], sc1[4*g+3]));
    }
    float tmax = fmaxf(fmaxf(fmaxf(t4[0], t4[1]), fmaxf(t4[2], t4[3])),
                       fmaxf(fmaxf(t4[4], t4[5]), fmaxf(t4[6], t4[7])));
    tmax = fmaxf(tmax, __shfl_xor(tmax, 32, 64));
    // defer-max (THR=8 log2 units)
    if (!__all(tmax <= m_run + 8.0f)) {
      const float mn = fmaxf(m_run, tmax);
      const float sf = __builtin_amdgcn_exp2f(m_run - mn);
      m_run = mn;
      l_run *= sf;
      #pragma unroll
      for (int r = 0; r < 16; r++) {
        const float sfq = __shfl(sf, (r & 3) + 8 * (r >> 2) + 4 * hi, 64);
        oacc0[r] *= sfq;
        oacc1[r] *= sfq;
      }
    }
    // p = exp2(sc - m_run); psum; cvt_pk packs (pk[st][g] covers s' = 8g+4*hi+(0..3))
    float ps4[8];
    #pragma unroll
    for (int g = 0; g < 4; g++) {
      #pragma unroll
      for (int m = 0; m < 4; m++) {
        sc0[4*g+m] = __builtin_amdgcn_exp2f(sc0[4*g+m] - m_run);
        sc1[4*g+m] = __builtin_amdgcn_exp2f(sc1[4*g+m] - m_run);
      }
      ps4[g]     = (sc0[4*g] + sc0[4*g+1]) + (sc0[4*g+2] + sc0[4*g+3]);
      ps4[4 + g] = (sc1[4*g] + sc1[4*g+1]) + (sc1[4*g+2] + sc1[4*g+3]);
    }
    float psum = ((ps4[0] + ps4[1]) + (ps4[2] + ps4[3])) + ((ps4[4] + ps4[5]) + (ps4[6] + ps4[7]));
    psum += __shfl_xor(psum, 32, 64);
    l_run += psum;
    uint2 pk0[4], pk1[4];
    #pragma unroll
    for (int g = 0; g < 4; g++) {
      pk0[g].x = cvtpk(sc0[4*g], sc0[4*g+1]);  pk0[g].y = cvtpk(sc0[4*g+2], sc0[4*g+3]);
      pk1[g].x = cvtpk(sc1[4*g], sc1[4*g+1]);  pk1[g].y = cvtpk(sc1[4*g+2], sc1[4*g+3]);
    }
    // PV: A = P[q][s] assembled in-register; B = V^T[d][s] from LDS
    __builtin_amdgcn_s_setprio(1);
    #pragma unroll
    for (int ks = 0; ks < 4; ks++) {
      const int gb = (ks & 1) * 2;
      const uint2 pa = (ks < 2) ? pk0[gb]     : pk1[gb];       // pack g = gb   (compile-time idx)
      const uint2 pb = (ks < 2) ? pk0[gb + 1] : pk1[gb + 1];   // pack g = gb+1
      uint2 own, snd;
      own.x = hi ? pb.x : pa.x;  own.y = hi ? pb.y : pa.y;
      snd.x = hi ? pa.x : pb.x;  snd.y = hi ? pa.y : pb.y;
      uint2 rcv;
      rcv.x = __shfl_xor((int)snd.x, 32, 64);
      rcv.y = __shfl_xor((int)snd.y, 32, 64);
      u32x4 fu;
      fu.x = hi ? rcv.x : own.x;  fu.y = hi ? rcv.y : own.y;   // j=0..3 (from hi_src=0)
      fu.z = hi ? own.x : rcv.x;  fu.w = hi ? own.y : rcv.y;   // j=4..7 (from hi_src=1)
      const bf16x8 pfrag = __builtin_bit_cast(bf16x8, fu);
      #pragma unroll
      for (int dt = 0; dt < 2; dt++) {
        const int d = dt * 32 + ql;
        bf16x8 vf = *(const bf16x8*)&Vl[cur][d * 64 + (((ks * 2 + hi) ^ (d & 7)) << 3)];
        if (dt == 0) oacc0 = __builtin_amdgcn_mfma_f32_32x32x16_bf16(pfrag, vf, oacc0, 0, 0, 0);
        else         oacc1 = __builtin_amdgcn_mfma_f32_32x32x16_bf16(pfrag, vf, oacc1, 0, 0, 0);
      }
    }
    __builtin_amdgcn_s_setprio(0);
  }
  // epilogue: O / l ; state for q-col qi lives at lane qi (both halves identical)
  const float linv = 1.0f / l_run;
  #pragma unroll
  for (int r = 0; r < 16; r++) {
    const int qi = (r & 3) + 8 * (r >> 2) + 4 * hi;
    const float lq = __shfl(linv, qi, 64);
    const int row = q0 + w * 32 + qi;
    O[(size_t)row * H_ + ql]      = f2bf(oacc0[r] * lq);
    O[(size_t)row * H_ + 32 + ql] = f2bf(oacc1[r] * lq);
  }
}

extern "C" void kernel_launch(void* const* d_in, const int* in_sizes, int n_in,
                              void* d_out, int out_size, void* d_ws, size_t ws_size,
                              hipStream_t stream) {
  const float* q  = (const float*)d_in[0];
  const float* k  = (const float*)d_in[1];
  const float* v  = (const float*)d_in[2];
  const float* Wq = (const float*)d_in[3];
  const float* bq = (const float*)d_in[4];
  const float* Wk = (const float*)d_in[5];
  const float* bk = (const float*)d_in[6];
  const float* Wv = (const float*)d_in[7];
  const float* bv = (const float*)d_in[8];
  const float* Wo = (const float*)d_in[9];
  const float* bo = (const float*)d_in[10];
  float* out = (float*)d_out;

  char* ws = (char*)d_ws;
  const size_t MB = 1024 * 1024;
  u16* xb   = (u16*)(ws);             // q,k,v bf16: 3 x 8MB      [0,24)
  u16* wt   = (u16*)(ws + 24 * MB);   // 4 x 2MB transposed W     [24,32)
  u16* qkp  = (u16*)(ws + 32 * MB);   // qp,kp: 2 x 8MB           [32,48)
  u16* vtp  = (u16*)(ws + 48 * MB);   // V^T [bh][d][s]: 8MB      [48,56)
  u16* ctx  = (u16*)(ws);             // reuse xb region after gemm_qkv

  cvt3  <<<dim3(4096, 1, 3), 256, 0, stream>>>(q, k, v, xb);
  wtrans<<<dim3(32, 32, 4),  256, 0, stream>>>(Wq, Wk, Wv, Wo, wt);
  gemm_qkv<<<dim3(8, 32, 3), 256, 0, stream>>>(xb, wt, bq, bk, bv, qkp, vtp);
  attn  <<<dim3(16, 32),     256, 0, stream>>>(qkp, qkp + (size_t)MR_ * H_, vtp, ctx);
  gemm_out<<<dim3(8, 32, 1), 256, 0, stream>>>(ctx, wt + (size_t)3 * H_ * K_, bo, out);
}